// Round 4
// baseline (77.785 us; speedup 1.0000x reference)
//
#include <hip/hip_runtime.h>
#include <hip/hip_bf16.h>

// Fused attention: q = x1@W^T+b, k = x2@W^T+b, scores = (q k^T)*8,
// p = softmax(scores), out = p @ x2.  B=4, S=T=4096, F=127, D=64, fp32 io.
//
// Round 3:
//  - wfrag_kernel: W -> split-bf16 B-fragments (32 KB, staged in d_out[0:32K],
//    overwritten later by attn's output -- safe, deterministic).
//  - proj_kernel: split-bf16 MFMA GEMM; emits Q AND K as pre-split hi/lo
//    fragment-layout (qhf/qlf/khf/klf) via per-wave LDS bounce. QSCALE folded
//    into Q (softmax runs in exp2 domain).
//  - x2repack_kernel: x2 -> PV-A fragments; f=127 pad slot = 1.0 so PV's MFMA
//    accumulates l = sum(p) into acc row 127 for free.
//  - attn_kernel: 256 blocks x 512 thr (8 waves). Block = 64 q-rows; wave =
//    (q-subtile w&1, key-quarter w>>1); wave pairs share K/x2 fragments (L1).
//    XCD-bijective swizzle: each batch's 64 blocks -> 2 XCDs (3 MB < L2).
//    Registers-only main loop, explicit double-buffered K prefetch, log2
//    online softmax with defer-max, LDS merge.
//
// ws: qhf [0,2MB) | qlf [2,4) | khf [4,6) | klf [6,8) | x2tf [8,12)

typedef __bf16 bf16x8 __attribute__((ext_vector_type(8)));
typedef float f32x16 __attribute__((ext_vector_type(16)));

#define S_DIM 4096
#define F_DIM 127
#define QSCALE 11.5415603271f  // 8 * log2(e)
#define THR 11.0f              // defer-max threshold (log2 units)

static __device__ __forceinline__ unsigned cvt_pk_bf16(float lo, float hi) {
  unsigned r;
  asm("v_cvt_pk_bf16_f32 %0, %1, %2" : "=v"(r) : "v"(lo), "v"(hi));
  return r;
}
static __device__ __forceinline__ float exp2_fast(float x) {
  float r;
  asm("v_exp_f32 %0, %1" : "=v"(r) : "v"(x));
  return r;
}
static __device__ __forceinline__ bf16x8 mk_bf16x8(unsigned w0, unsigned w1,
                                                   unsigned w2, unsigned w3) {
  unsigned t[4] = {w0, w1, w2, w3};
  bf16x8 r;
  __builtin_memcpy(&r, t, 16);
  return r;
}
static __device__ __forceinline__ bf16x8 u4_bf16x8(uint4 v) {
  bf16x8 r;
  __builtin_memcpy(&r, &v, 16);
  return r;
}

// ------------------------------------------------------------- W fragments
// grid 4 x 256. thread gid -> (dt, kk, lane). wf[((dt*8+kk)*64+lane)*2+{0,1}]
// = {hi, lo} uint4 B-fragment of W (col d = dt*32+(lane&31)).
__global__ __launch_bounds__(256) void wfrag_kernel(const float* __restrict__ W,
                                                    uint4* __restrict__ wf) {
  const int gid = blockIdx.x * 256 + threadIdx.x;  // [0,1024)
  const int dt = gid >> 9;
  const int kk = (gid >> 6) & 7;
  const int lane = gid & 63;
  const int d = dt * 32 + (lane & 31);
  const int f0b = kk * 16 + (lane >> 5) * 8;
  const float* wr = W + (long)d * F_DIM;
  unsigned hw[4], lw[4];
#pragma unroll
  for (int g = 0; g < 4; ++g) {
    const int f0 = f0b + 2 * g;
    const float v0 = (f0 < F_DIM) ? wr[f0] : 0.f;
    const float v1 = (f0 + 1 < F_DIM) ? wr[f0 + 1] : 0.f;
    const unsigned h = cvt_pk_bf16(v0, v1);
    const float l0 = v0 - __uint_as_float(h << 16);
    const float l1 = v1 - __uint_as_float(h & 0xffff0000u);
    hw[g] = h;
    lw[g] = cvt_pk_bf16(l0, l1);
  }
  wf[((dt * 8 + kk) * 64 + lane) * 2 + 0] = make_uint4(hw[0], hw[1], hw[2], hw[3]);
  wf[((dt * 8 + kk) * 64 + lane) * 2 + 1] = make_uint4(lw[0], lw[1], lw[2], lw[3]);
}

// ---------------------------------------------------------------- projection
// grid 256 x 256. blocks [0,128) -> Q from x1, [128,256) -> K from x2.
// Block = 128 rows (4 waves x 32). Epilogue bounces through LDS to emit
// pre-split hi/lo fragments: dst[b][tile][kk][lane] = one uint4.
__global__ __launch_bounds__(256) void proj_kernel(
    const float* __restrict__ x1, const float* __restrict__ x2,
    const uint4* __restrict__ wf, const float* __restrict__ bias,
    uint4* __restrict__ qhf, uint4* __restrict__ qlf,
    uint4* __restrict__ khf, uint4* __restrict__ klf) {
  __shared__ unsigned kstage[4][32 * 66];  // per-wave; stride 66 (2-way free)
  const int tid = threadIdx.x;
  const int wave = tid >> 6;
  const int lane = tid & 63;
  const int arow = lane & 31;
  const int half = lane >> 5;
  const int bi = blockIdx.x;
  const bool isK = bi >= 128;
  const float* x = isK ? x2 : x1;
  const int grow0 = (bi & 127) * 128 + wave * 32;
  const float* xrow = x + (long)(grow0 + arow) * F_DIM;

  // A-fragments: x[row][k], row=lane&31, k = kk*16 + half*8 + j. Split hi/lo
  // via cvt_pk pairs.
  bf16x8 xh[8], xl[8];
#pragma unroll
  for (int kk = 0; kk < 8; ++kk) {
    unsigned hw[4], lw[4];
#pragma unroll
    for (int g = 0; g < 4; ++g) {
      const int f0 = kk * 16 + half * 8 + 2 * g;
      const float v0 = (f0 < F_DIM) ? xrow[f0] : 0.f;
      const float v1 = (f0 + 1 < F_DIM) ? xrow[f0 + 1] : 0.f;
      const unsigned h = cvt_pk_bf16(v0, v1);
      const float l0 = v0 - __uint_as_float(h << 16);
      const float l1 = v1 - __uint_as_float(h & 0xffff0000u);
      hw[g] = h;
      lw[g] = cvt_pk_bf16(l0, l1);
    }
    xh[kk] = mk_bf16x8(hw[0], hw[1], hw[2], hw[3]);
    xl[kk] = mk_bf16x8(lw[0], lw[1], lw[2], lw[3]);
  }

  f32x16 acc0, acc1;
#pragma unroll
  for (int r = 0; r < 16; ++r) {
    acc0[r] = 0.f;
    acc1[r] = 0.f;
  }
#pragma unroll
  for (int kk = 0; kk < 8; ++kk) {
    const bf16x8 wh0 = u4_bf16x8(wf[((0 * 8 + kk) * 64 + lane) * 2 + 0]);
    const bf16x8 wl0 = u4_bf16x8(wf[((0 * 8 + kk) * 64 + lane) * 2 + 1]);
    const bf16x8 wh1 = u4_bf16x8(wf[((1 * 8 + kk) * 64 + lane) * 2 + 0]);
    const bf16x8 wl1 = u4_bf16x8(wf[((1 * 8 + kk) * 64 + lane) * 2 + 1]);
    acc0 = __builtin_amdgcn_mfma_f32_32x32x16_bf16(xh[kk], wh0, acc0, 0, 0, 0);
    acc0 = __builtin_amdgcn_mfma_f32_32x32x16_bf16(xh[kk], wl0, acc0, 0, 0, 0);
    acc0 = __builtin_amdgcn_mfma_f32_32x32x16_bf16(xl[kk], wh0, acc0, 0, 0, 0);
    acc1 = __builtin_amdgcn_mfma_f32_32x32x16_bf16(xh[kk], wh1, acc1, 0, 0, 0);
    acc1 = __builtin_amdgcn_mfma_f32_32x32x16_bf16(xh[kk], wl1, acc1, 0, 0, 0);
    acc1 = __builtin_amdgcn_mfma_f32_32x32x16_bf16(xl[kk], wh1, acc1, 0, 0, 0);
  }

  // Epilogue. C layout: row=(r&3)+8*(r>>2)+4*half (= t in tile), col=d.
  unsigned* kst = kstage[wave];
#pragma unroll
  for (int dt = 0; dt < 2; ++dt) {
    const f32x16 acc = dt ? acc1 : acc0;
    const int d = dt * 32 + arow;
    const float bd = bias[d];
#pragma unroll
    for (int r = 0; r < 16; r += 2) {
      const int row0 = (r & 3) + 8 * (r >> 2) + 4 * half;  // rows row0,row0+1
      float v0 = acc[r] + bd;
      float v1 = acc[r + 1] + bd;
      if (!isK) {
        v0 *= QSCALE;
        v1 *= QSCALE;
      }
      const unsigned h = cvt_pk_bf16(v0, v1);
      const float l0 = v0 - __uint_as_float(h << 16);
      const float l1 = v1 - __uint_as_float(h & 0xffff0000u);
      const unsigned l = cvt_pk_bf16(l0, l1);
      kst[row0 * 66 + d] = (h & 0xffffu) | (l << 16);
      kst[(row0 + 1) * 66 + d] = (h >> 16) | (l & 0xffff0000u);
    }
  }

  const int b = grow0 >> 12;
  const int tile = (grow0 & (S_DIM - 1)) >> 5;
  uint4* dh = (isK ? khf : qhf) + ((long)(b * 128 + tile) * 4) * 64 + lane;
  uint4* dl = (isK ? klf : qlf) + ((long)(b * 128 + tile) * 4) * 64 + lane;
#pragma unroll
  for (int kk = 0; kk < 4; ++kk) {
    const int d0 = kk * 16 + half * 8;
    unsigned w[8];
#pragma unroll
    for (int j = 0; j < 8; ++j) w[j] = kst[arow * 66 + d0 + j];
    unsigned hw[4], lw[4];
#pragma unroll
    for (int g = 0; g < 4; ++g) {
      hw[g] = (w[2 * g] & 0xffffu) | (w[2 * g + 1] << 16);
      lw[g] = (w[2 * g] >> 16) | (w[2 * g + 1] & 0xffff0000u);
    }
    dh[kk * 64] = make_uint4(hw[0], hw[1], hw[2], hw[3]);
    dl[kk * 64] = make_uint4(lw[0], lw[1], lw[2], lw[3]);
  }
}

// ------------------------------------------------------ x2 -> PV-A fragments
// grid 1024 x 256. f==127 pad slot = 1.0 -> PV accumulates l into row 127.
__global__ __launch_bounds__(256) void x2repack_kernel(
    const float* __restrict__ x2, uint4* __restrict__ x2tf) {
  const int tid = threadIdx.x;
  const int bi = blockIdx.x;
  const int b = bi >> 8;
  const int tt = bi & 255;
  const int fb = tid >> 6;
  const int l = tid & 63;
  const int t0 = tt * 16 + ((l >> 5) << 3);
  const int f = fb * 32 + (l & 31);
  const float* src = x2 + ((long)b * S_DIM + t0) * F_DIM + f;
  unsigned w[4];
#pragma unroll
  for (int g = 0; g < 4; ++g) {
    const float v0 = (f < F_DIM) ? src[(long)(2 * g) * F_DIM] : 1.0f;
    const float v1 = (f < F_DIM) ? src[(long)(2 * g + 1) * F_DIM] : 1.0f;
    w[g] = cvt_pk_bf16(v0, v1);
  }
  x2tf[((long)(b * 256 + tt) * 4 + fb) * 64 + l] = make_uint4(w[0], w[1], w[2], w[3]);
}

// ------------------------------------------------------------------ attention
// grid 256 x 512. XCD-swizzled: logical L -> batch b = L>>6, q0 = (L&63)*64.
// wave w: q-subtile sub=w&1 (32 rows), key-quarter qtr=w>>1 (32 tiles).
__global__ __launch_bounds__(512, 2) void attn_kernel(
    const uint4* __restrict__ qhf, const uint4* __restrict__ qlf,
    const uint4* __restrict__ khf, const uint4* __restrict__ klf,
    const uint4* __restrict__ x2tf, float* __restrict__ out) {
  const int tid = threadIdx.x;
  const int lane = tid & 63;
  const int wave = tid >> 6;
  const int col = lane & 31;
  const int half = lane >> 5;
  const int sub = wave & 1;
  const int qtr = wave >> 1;
  // bijective XCD swizzle: xcd = bi&7 -> batch pair; 32 blocks/XCD,
  // per-XCD working set = one batch's khf/klf/x2tf = 3 MB < 4 MiB L2.
  const int bi = blockIdx.x;
  const int xcd = bi & 7;
  const int slot = bi >> 3;
  const int L = (xcd >> 1) * 64 + slot * 2 + (xcd & 1);
  const int b = L >> 6;
  const int q0 = (L & 63) << 6;

  // Q fragments (pre-split): subtile's 32 q-rows.
  const int qtile = ((q0 + sub * 32) & (S_DIM - 1)) >> 5;
  bf16x8 qh[4], ql[4];
#pragma unroll
  for (int kk = 0; kk < 4; ++kk) {
    qh[kk] = u4_bf16x8(qhf[((long)(b * 128 + qtile) * 4 + kk) * 64 + lane]);
    ql[kk] = u4_bf16x8(qlf[((long)(b * 128 + qtile) * 4 + kk) * 64 + lane]);
  }

  const uint4* khfp = khf + (long)b * 128 * 4 * 64;
  const uint4* klfp = klf + (long)b * 128 * 4 * 64;
  const uint4* xfp = x2tf + (long)b * 256 * 4 * 64;

  f32x16 a0, a1, a2, a3;
#pragma unroll
  for (int r = 0; r < 16; ++r) {
    a0[r] = 0.f; a1[r] = 0.f; a2[r] = 0.f; a3[r] = 0.f;
  }
  float m = -INFINITY;

  uint4 KA[8], KB[8];
  {
    const int t0_ = qtr;  // tile for i=0
#pragma unroll
    for (int kk = 0; kk < 4; ++kk) {
      KA[kk] = khfp[(t0_ * 4 + kk) * 64 + lane];
      KA[4 + kk] = klfp[(t0_ * 4 + kk) * 64 + lane];
    }
  }

  auto body = [&](const uint4 (&C)[8], uint4 (&N)[8], int i) {
    const int tile = (i << 2) + qtr;
    // PV operand loads for this tile (consumed after QK+softmax)
    uint4 xv[8];
#pragma unroll
    for (int kf = 0; kf < 2; ++kf)
#pragma unroll
      for (int fb = 0; fb < 4; ++fb)
        xv[kf * 4 + fb] = xfp[((tile * 2 + kf) * 4 + fb) * 64 + lane];
    // prefetch next K tile into N
    if (i < 31) {
      const int tn = ((i + 1) << 2) + qtr;
#pragma unroll
      for (int kk = 0; kk < 4; ++kk) {
        N[kk] = khfp[(tn * 4 + kk) * 64 + lane];
        N[4 + kk] = klfp[(tn * 4 + kk) * 64 + lane];
      }
    }
    // S^T = K . Q^T (3-term split-bf16); C layout: col=q, row=key
    f32x16 st;
#pragma unroll
    for (int r = 0; r < 16; ++r) st[r] = 0.f;
#pragma unroll
    for (int kk = 0; kk < 4; ++kk) {
      const bf16x8 kv = u4_bf16x8(C[kk]);
      const bf16x8 lv = u4_bf16x8(C[4 + kk]);
      st = __builtin_amdgcn_mfma_f32_32x32x16_bf16(kv, qh[kk], st, 0, 0, 0);
      st = __builtin_amdgcn_mfma_f32_32x32x16_bf16(kv, ql[kk], st, 0, 0, 0);
      st = __builtin_amdgcn_mfma_f32_32x32x16_bf16(lv, qh[kk], st, 0, 0, 0);
    }
    // online softmax (log2 domain), defer-max
    float pmax = st[0];
#pragma unroll
    for (int r = 1; r < 16; ++r) pmax = fmaxf(pmax, st[r]);
    pmax = fmaxf(pmax, __shfl_xor(pmax, 32));
    if (__any(pmax > m + THR)) {
      const float mnew = fmaxf(m, pmax);
      const float sc = exp2_fast(m - mnew);
#pragma unroll
      for (int r = 0; r < 16; ++r) {
        a0[r] *= sc; a1[r] *= sc; a2[r] *= sc; a3[r] *= sc;
      }
      m = mnew;
    }
    unsigned pg[4][2];
#pragma unroll
    for (int g = 0; g < 4; ++g) {
      pg[g][0] = cvt_pk_bf16(exp2_fast(st[4 * g + 0] - m),
                             exp2_fast(st[4 * g + 1] - m));
      pg[g][1] = cvt_pk_bf16(exp2_fast(st[4 * g + 2] - m),
                             exp2_fast(st[4 * g + 3] - m));
    }
    // pack P rows into PV B-fragments (one permlane32_swap pair per kk)
#pragma unroll
    for (int kk = 0; kk < 2; ++kk) {
      unsigned x0 = pg[2 * kk][0], y0 = pg[2 * kk + 1][0];
      unsigned x1 = pg[2 * kk][1], y1 = pg[2 * kk + 1][1];
      asm("v_permlane32_swap_b32 %0, %1" : "+v"(x0), "+v"(y0));
      asm("v_permlane32_swap_b32 %0, %1" : "+v"(x1), "+v"(y1));
      const bf16x8 pf = mk_bf16x8(x0, x1, y0, y1);
      a0 = __builtin_amdgcn_mfma_f32_32x32x16_bf16(u4_bf16x8(xv[kk * 4 + 0]),
                                                   pf, a0, 0, 0, 0);
      a1 = __builtin_amdgcn_mfma_f32_32x32x16_bf16(u4_bf16x8(xv[kk * 4 + 1]),
                                                   pf, a1, 0, 0, 0);
      a2 = __builtin_amdgcn_mfma_f32_32x32x16_bf16(u4_bf16x8(xv[kk * 4 + 2]),
                                                   pf, a2, 0, 0, 0);
      a3 = __builtin_amdgcn_mfma_f32_32x32x16_bf16(u4_bf16x8(xv[kk * 4 + 3]),
                                                   pf, a3, 0, 0, 0);
    }
  };

  for (int i = 0; i < 32; i += 2) {
    body(KA, KB, i);
    body(KB, KA, i + 1);
  }

  // -------- merge: per subtile, 4 waves' (m, acc) in LDS. l is acc row 127.
  __shared__ float mbuf[8][32];
  __shared__ float accb[2][128 * 33];
  if (lane < 32) mbuf[wave][col] = m;
  __syncthreads();
  float mstar = mbuf[sub][col];
#pragma unroll
  for (int w = 1; w < 4; ++w) mstar = fmaxf(mstar, mbuf[sub + 2 * w][col]);
  const float wsc = exp2_fast(m - mstar);
  float* buf = accb[sub];
  auto emit = [&](const f32x16& av, int fb, bool first) {
#pragma unroll
    for (int r = 0; r < 16; ++r) {
      const int f = fb * 32 + (r & 3) + 8 * (r >> 2) + 4 * half;
      const float v = av[r] * wsc;
      if (first) buf[f * 33 + col] = v;
      else buf[f * 33 + col] += v;
    }
  };
  for (int p = 0; p < 4; ++p) {
    if (qtr == p) {
      const bool first = (p == 0);
      emit(a0, 0, first);
      emit(a1, 1, first);
      emit(a2, 2, first);
      emit(a3, 3, first);
    }
    __syncthreads();
  }

  // readout: 512 threads, q64 = tid>>3 (64 rows), fg = tid&7 (16 f each)
  const int q64 = tid >> 3;
  const int fg = tid & 7;
  const int s2 = q64 >> 5;
  const int qq = q64 & 31;
  const float inv = 1.0f / accb[s2][127 * 33 + qq];
  float* ob = out + ((long)(b * S_DIM + q0 + q64)) * F_DIM;
#pragma unroll
  for (int j = 0; j < 16; ++j) {
    const int f = fg * 16 + j;
    if (f < F_DIM) ob[f] = accb[s2][f * 33 + qq] * inv;
  }
}

extern "C" void kernel_launch(void* const* d_in, const int* in_sizes, int n_in,
                              void* d_out, int out_size, void* d_ws,
                              size_t ws_size, hipStream_t stream) {
  const float* x1 = (const float*)d_in[0];
  const float* x2 = (const float*)d_in[1];
  const float* W = (const float*)d_in[2];
  const float* bias = (const float*)d_in[3];
  float* out = (float*)d_out;

  char* ws = (char*)d_ws;
  uint4* qhf = (uint4*)ws;                     // 2 MB
  uint4* qlf = (uint4*)(ws + (2l << 20));      // 2 MB
  uint4* khf = (uint4*)(ws + (4l << 20));      // 2 MB
  uint4* klf = (uint4*)(ws + (6l << 20));      // 2 MB
  uint4* x2tf = (uint4*)(ws + (8l << 20));     // 4 MB
  uint4* wf = (uint4*)d_out;                   // 32 KB scratch, overwritten
                                               // by attn's output writes

  hipLaunchKernelGGL(wfrag_kernel, dim3(4), dim3(256), 0, stream, W, wf);
  hipLaunchKernelGGL(proj_kernel, dim3(256), dim3(256), 0, stream, x1, x2, wf,
                     bias, qhf, qlf, khf, klf);
  hipLaunchKernelGGL(x2repack_kernel, dim3(1024), dim3(256), 0, stream, x2,
                     x2tf);
  hipLaunchKernelGGL(attn_kernel, dim3(256), dim3(512), 0, stream, qhf, qlf,
                     khf, klf, x2tf, out);
}